// Round 2
// baseline (2551.546 us; speedup 1.0000x reference)
//
#include <hip/hip_runtime.h>

// Problem dims (fixed)
#define BB 2
#define LL 1024
#define DD 1024
#define HH 16
#define HD 64
#define DFFN 4096
#define MM (BB*LL)   // 2048 rows

using u16 = unsigned short;

__device__ __forceinline__ float b2f(u16 u) {
  union { unsigned int i; float f; } v; v.i = ((unsigned int)u) << 16; return v.f;
}
__device__ __forceinline__ u16 f2b(float f) {
  union { float f; unsigned int i; } v; v.f = f;
  unsigned int x = v.i;
  return (u16)((x + 0x7fffu + ((x >> 16) & 1u)) >> 16);  // RNE, finite values
}
__device__ __forceinline__ float gelu_exact(float x) {
  return 0.5f * x * (1.0f + erff(x * 0.70710678118654752f));
}

// ---------------- rmsnorm (fp32 in, fp32 weight, bf16 out) ----------------
__global__ __launch_bounds__(256) void rmsnorm_kernel(const float* __restrict__ x,
                                                      const float* __restrict__ w,
                                                      u16* __restrict__ out) {
  const int row = blockIdx.x, t = threadIdx.x;
  const float4 v = reinterpret_cast<const float4*>(x + (size_t)row * DD)[t];
  float ss = v.x*v.x + v.y*v.y + v.z*v.z + v.w*v.w;
  #pragma unroll
  for (int o = 32; o > 0; o >>= 1) ss += __shfl_down(ss, o);
  __shared__ float red[4];
  if ((t & 63) == 0) red[t >> 6] = ss;
  __syncthreads();
  const float inv = rsqrtf((red[0] + red[1] + red[2] + red[3]) * (1.0f / DD) + 1e-5f);
  const float4 wv = reinterpret_cast<const float4*>(w)[t];
  ushort4 o;
  o.x = f2b(v.x * inv * wv.x);
  o.y = f2b(v.y * inv * wv.y);
  o.z = f2b(v.z * inv * wv.z);
  o.w = f2b(v.w * inv * wv.w);
  reinterpret_cast<ushort4*>(out + (size_t)row * DD)[t] = o;
}

// ---------------- GEMM: C[M,N] = A[M,K](bf16) @ W[N,K](fp32)^T ----------------
// ACT: 0 none, 1 exact gelu.  RES: 0 -> bf16 Cb out; 1 -> Co(f32) = resid(f32) + acc + bias(f32)
template<int ACT, int RES>
__global__ __launch_bounds__(256) void gemm_kernel(const u16* __restrict__ A,
                                                   const float* __restrict__ W,
                                                   u16* __restrict__ Cb,
                                                   const float* __restrict__ resid,
                                                   float* __restrict__ Co,
                                                   const float* __restrict__ bias,
                                                   int N, int K) {
  __shared__ float As[64][33];
  __shared__ float Bs[64][33];
  const int t = threadIdx.x;
  const int tx = t & 15, ty = t >> 4;
  const int m0 = blockIdx.y * 64, n0 = blockIdx.x * 64;
  const int lrow = t >> 2, lco = t & 3;

  float acc[4][4] = {};
  for (int kt = 0; kt < K; kt += 32) {
    union { uint4 u; u16 s[8]; } pa;
    pa.u = *reinterpret_cast<const uint4*>(A + (size_t)(m0 + lrow) * K + kt + lco * 8);
    const float* wp = W + (size_t)(n0 + lrow) * K + kt + lco * 8;
    const float4 w0 = reinterpret_cast<const float4*>(wp)[0];
    const float4 w1 = reinterpret_cast<const float4*>(wp)[1];
    __syncthreads();
    #pragma unroll
    for (int j = 0; j < 8; j++) As[lrow][lco * 8 + j] = b2f(pa.s[j]);
    Bs[lrow][lco * 8 + 0] = w0.x; Bs[lrow][lco * 8 + 1] = w0.y;
    Bs[lrow][lco * 8 + 2] = w0.z; Bs[lrow][lco * 8 + 3] = w0.w;
    Bs[lrow][lco * 8 + 4] = w1.x; Bs[lrow][lco * 8 + 5] = w1.y;
    Bs[lrow][lco * 8 + 6] = w1.z; Bs[lrow][lco * 8 + 7] = w1.w;
    __syncthreads();
    #pragma unroll 8
    for (int kk = 0; kk < 32; kk++) {
      float ar[4], br[4];
      #pragma unroll
      for (int i = 0; i < 4; i++) ar[i] = As[ty * 4 + i][kk];
      #pragma unroll
      for (int j = 0; j < 4; j++) br[j] = Bs[tx * 4 + j][kk];
      #pragma unroll
      for (int i = 0; i < 4; i++)
        #pragma unroll
        for (int j = 0; j < 4; j++)
          acc[i][j] += ar[i] * br[j];
    }
  }

  const int r0 = m0 + ty * 4, c0 = n0 + tx * 4;
  if (RES == 0) {
    #pragma unroll
    for (int i = 0; i < 4; i++) {
      float vv[4];
      #pragma unroll
      for (int j = 0; j < 4; j++) {
        float val = acc[i][j];
        if (ACT == 1) val = gelu_exact(val);
        vv[j] = val;
      }
      ushort4 pk; pk.x = f2b(vv[0]); pk.y = f2b(vv[1]); pk.z = f2b(vv[2]); pk.w = f2b(vv[3]);
      *reinterpret_cast<ushort4*>(Cb + (size_t)(r0 + i) * N + c0) = pk;
    }
  } else {
    #pragma unroll
    for (int i = 0; i < 4; i++) {
      float4 rv = *reinterpret_cast<const float4*>(resid + (size_t)(r0 + i) * N + c0);
      float b0 = 0.f, b1 = 0.f, b2 = 0.f, b3 = 0.f;
      if (bias != nullptr) {
        b0 = bias[c0 + 0]; b1 = bias[c0 + 1];
        b2 = bias[c0 + 2]; b3 = bias[c0 + 3];
      }
      float4 ov;
      ov.x = rv.x + acc[i][0] + b0;
      ov.y = rv.y + acc[i][1] + b1;
      ov.z = rv.z + acc[i][2] + b2;
      ov.w = rv.w + acc[i][3] + b3;
      *reinterpret_cast<float4*>(Co + (size_t)(r0 + i) * N + c0) = ov;
    }
  }
}

// ---------------- causal linear attention ----------------
// a[b,l,h,:] = sum_{j<=l} (Q_l . K_j) V_j   per (b,h); Q/K/V bf16 [B*L, D], head h at cols h*64..+63
// grid: (qt=16, h=16, b=2), block 256. LDS: Qs/Ks/Ss fp32 rotated, Vs bf16 padded (total ~56.6KB)
__global__ __launch_bounds__(256) void attn_kernel(const u16* __restrict__ Q,
                                                   const u16* __restrict__ K,
                                                   const u16* __restrict__ V,
                                                   u16* __restrict__ O) {
  __shared__ float Qs[64][64], Ks[64][64], Ss[64][64];  // rotation-swizzled cols
  __shared__ u16 Vs[64][68];                            // plain, padded
  const int qt = blockIdx.x, h = blockIdx.y, b = blockIdx.z;
  const int t = threadIdx.x;
  const int tx = t & 15, ty = t >> 4;
  const int r0 = ty * 4, c0 = tx * 4;
  const int lrow = t >> 2, le0 = (t & 3) * 16;

  {  // load Q tile once
    const u16* qp = Q + ((size_t)(b * LL + qt * 64 + lrow) * DD + h * HD + le0);
    union { uint4 u[2]; u16 s[16]; } pk;
    pk.u[0] = reinterpret_cast<const uint4*>(qp)[0];
    pk.u[1] = reinterpret_cast<const uint4*>(qp)[1];
    #pragma unroll
    for (int j = 0; j < 16; j++) Qs[lrow][(le0 + j + lrow) & 63] = b2f(pk.s[j]);
  }

  float acc[4][4] = {};
  for (int jt = 0; jt <= qt; jt++) {
    __syncthreads();  // Qs visible (1st iter); prev tile's reads done before K/V overwrite
    {
      const u16* kp = K + ((size_t)(b * LL + jt * 64 + lrow) * DD + h * HD + le0);
      const u16* vp = V + ((size_t)(b * LL + jt * 64 + lrow) * DD + h * HD + le0);
      union { uint4 u[2]; u16 s[16]; } ku, vu;
      ku.u[0] = reinterpret_cast<const uint4*>(kp)[0];
      ku.u[1] = reinterpret_cast<const uint4*>(kp)[1];
      vu.u[0] = reinterpret_cast<const uint4*>(vp)[0];
      vu.u[1] = reinterpret_cast<const uint4*>(vp)[1];
      #pragma unroll
      for (int j = 0; j < 16; j++) Ks[lrow][(le0 + j + lrow) & 63] = b2f(ku.s[j]);
      #pragma unroll
      for (int j = 0; j < 4; j++) {
        ushort4 pv; pv.x = vu.s[j*4+0]; pv.y = vu.s[j*4+1]; pv.z = vu.s[j*4+2]; pv.w = vu.s[j*4+3];
        *reinterpret_cast<ushort4*>(&Vs[lrow][le0 + j * 4]) = pv;
      }
    }
    __syncthreads();
    // S tile = Q K^T  (dot over 64 head dims)
    float sacc[4][4] = {};
    #pragma unroll 4
    for (int kk = 0; kk < 64; kk++) {
      float ar[4], br[4];
      #pragma unroll
      for (int i = 0; i < 4; i++) ar[i] = Qs[r0 + i][(kk + r0 + i) & 63];
      #pragma unroll
      for (int j = 0; j < 4; j++) br[j] = Ks[c0 + j][(kk + c0 + j) & 63];
      #pragma unroll
      for (int i = 0; i < 4; i++)
        #pragma unroll
        for (int j = 0; j < 4; j++)
          sacc[i][j] += ar[i] * br[j];
    }
    const bool diag = (jt == qt);
    #pragma unroll
    for (int i = 0; i < 4; i++)
      #pragma unroll
      for (int j = 0; j < 4; j++) {
        float sv = sacc[i][j];
        if (diag && (c0 + j > r0 + i)) sv = 0.0f;  // causal: keep j<=l (inclusive)
        Ss[r0 + i][(c0 + j + r0 + i) & 63] = sv;
      }
    __syncthreads();
    // acc += S @ V
    #pragma unroll 4
    for (int c = 0; c < 64; c++) {
      float sr[4], vr[4];
      #pragma unroll
      for (int i = 0; i < 4; i++) sr[i] = Ss[r0 + i][(c + r0 + i) & 63];
      const ushort4 pv = *reinterpret_cast<const ushort4*>(&Vs[c][c0]);
      vr[0] = b2f(pv.x); vr[1] = b2f(pv.y); vr[2] = b2f(pv.z); vr[3] = b2f(pv.w);
      #pragma unroll
      for (int i = 0; i < 4; i++)
        #pragma unroll
        for (int j = 0; j < 4; j++)
          acc[i][j] += sr[i] * vr[j];
    }
  }

  #pragma unroll
  for (int i = 0; i < 4; i++) {
    ushort4 pk;
    pk.x = f2b(acc[i][0]); pk.y = f2b(acc[i][1]);
    pk.z = f2b(acc[i][2]); pk.w = f2b(acc[i][3]);
    *reinterpret_cast<ushort4*>(O + ((size_t)(b * LL + qt * 64 + r0 + i) * DD + h * HD + c0)) = pk;
  }
}

// ---------------- host ----------------
extern "C" void kernel_launch(void* const* d_in, const int* in_sizes, int n_in,
                              void* d_out, int out_size, void* d_ws, size_t ws_size,
                              hipStream_t stream) {
  const float* x_in = (const float*)d_in[0];
  const float* qw   = (const float*)d_in[1];
  const float* kw   = (const float*)d_in[2];
  const float* vw   = (const float*)d_in[3];
  const float* ow   = (const float*)d_in[4];
  const float* pn   = (const float*)d_in[5];
  const float* ln   = (const float*)d_in[6];
  const float* fcw  = (const float*)d_in[7];
  const float* fc2w = (const float*)d_in[8];
  const float* fc2b = (const float*)d_in[9];

  char* ws = (char*)d_ws;
  float* xf = (float*)ws;                      // 0..8 MB  fp32 residual stream
  u16* h = (u16*)(ws + (size_t)(8  << 20));    // 8..12 MB  (bf16 2048x1024)
  u16* q = (u16*)(ws + (size_t)(12 << 20));    // 12..16
  u16* k = (u16*)(ws + (size_t)(16 << 20));    // 16..20
  u16* v = (u16*)(ws + (size_t)(20 << 20));    // 20..24
  u16* a = h;                                  // reuse h (dead after V gemm)
  u16* m = q;                                  // reuse q (dead after attn)
  u16* f = (u16*)(ws + (size_t)(16 << 20));    // 16..32 MB (bf16 2048x4096; k,v dead)

  const dim3 gD(DD / 64, MM / 64);     // (16,32)
  const dim3 gF(DFFN / 64, MM / 64);   // (64,32)

  for (int i = 0; i < 2; i++) {
    const float* qwi  = qw   + (size_t)i * DD * DD;
    const float* kwi  = kw   + (size_t)i * DD * DD;
    const float* vwi  = vw   + (size_t)i * DD * DD;
    const float* owi  = ow   + (size_t)i * DD * DD;
    const float* fcwi = fcw  + (size_t)i * DFFN * DD;
    const float* f2wi = fc2w + (size_t)i * DD * DFFN;
    const float* src  = (i == 0) ? x_in : xf;        // residual stream into this layer

    rmsnorm_kernel<<<MM, 256, 0, stream>>>(src, pn + i * DD, h);
    gemm_kernel<0, 0><<<gD, 256, 0, stream>>>(h, qwi, q, nullptr, nullptr, nullptr, DD, DD);
    gemm_kernel<0, 0><<<gD, 256, 0, stream>>>(h, kwi, k, nullptr, nullptr, nullptr, DD, DD);
    gemm_kernel<0, 0><<<gD, 256, 0, stream>>>(h, vwi, v, nullptr, nullptr, nullptr, DD, DD);
    attn_kernel<<<dim3(LL / 64, HH, BB), 256, 0, stream>>>(q, k, v, a);
    gemm_kernel<0, 1><<<gD, 256, 0, stream>>>(a, owi, nullptr, src, xf, nullptr, DD, DD);
    rmsnorm_kernel<<<MM, 256, 0, stream>>>(xf, ln + i * DD, m);
    gemm_kernel<1, 0><<<gF, 256, 0, stream>>>(m, fcwi, f, nullptr, nullptr, nullptr, DFFN, DD);
    float* co = (i == 1) ? (float*)d_out : xf;
    gemm_kernel<0, 1><<<gD, 256, 0, stream>>>(f, f2wi, nullptr, xf, co, fc2b + i * DD, DD, DFFN);
  }
}

// Round 3
// 951.718 us; speedup vs baseline: 2.6810x; 2.6810x over previous
//
#include <hip/hip_runtime.h>

// Problem dims (fixed)
#define BB 2
#define LL 1024
#define DD 1024
#define HH 16
#define HD 64
#define DFFN 4096
#define MM (BB*LL)   // 2048 rows
#define QS 3072      // fused QKV row stride

using u16 = unsigned short;
typedef __bf16 bf16x8 __attribute__((ext_vector_type(8)));
typedef float f32x4 __attribute__((ext_vector_type(4)));

__device__ __forceinline__ float b2f(u16 u) {
  union { unsigned int i; float f; } v; v.i = ((unsigned int)u) << 16; return v.f;
}
__device__ __forceinline__ u16 f2b(float f) {
  union { float f; unsigned int i; } v; v.f = f;
  unsigned int x = v.i;
  return (u16)((x + 0x7fffu + ((x >> 16) & 1u)) >> 16);  // RNE, finite values
}
__device__ __forceinline__ float gelu_exact(float x) {
  return 0.5f * x * (1.0f + erff(x * 0.70710678118654752f));
}
__device__ __forceinline__ void gl2lds16(const void* g, void* l) {
  __builtin_amdgcn_global_load_lds((const __attribute__((address_space(1))) void*)g,
                                   (__attribute__((address_space(3))) void*)l, 16, 0, 0);
}

// ---------------- weight cast fp32 -> bf16, 8 elems/thread ----------------
__global__ __launch_bounds__(256) void castw_kernel(const float* __restrict__ in,
                                                    u16* __restrict__ out, int n8) {
  int i = blockIdx.x * 256 + threadIdx.x;
  if (i >= n8) return;
  const float4 a = reinterpret_cast<const float4*>(in)[2 * i];
  const float4 b = reinterpret_cast<const float4*>(in)[2 * i + 1];
  uint4 o;
  o.x = (unsigned)f2b(a.x) | ((unsigned)f2b(a.y) << 16);
  o.y = (unsigned)f2b(a.z) | ((unsigned)f2b(a.w) << 16);
  o.z = (unsigned)f2b(b.x) | ((unsigned)f2b(b.y) << 16);
  o.w = (unsigned)f2b(b.z) | ((unsigned)f2b(b.w) << 16);
  reinterpret_cast<uint4*>(out)[i] = o;
}

// ---------------- rmsnorm (fp32 in, fp32 weight, bf16 out) ----------------
__global__ __launch_bounds__(256) void rmsnorm_kernel(const float* __restrict__ x,
                                                      const float* __restrict__ w,
                                                      u16* __restrict__ out) {
  const int row = blockIdx.x, t = threadIdx.x;
  const float4 v = reinterpret_cast<const float4*>(x + (size_t)row * DD)[t];
  float ss = v.x*v.x + v.y*v.y + v.z*v.z + v.w*v.w;
  #pragma unroll
  for (int o = 32; o > 0; o >>= 1) ss += __shfl_down(ss, o);
  __shared__ float red[4];
  if ((t & 63) == 0) red[t >> 6] = ss;
  __syncthreads();
  const float inv = rsqrtf((red[0] + red[1] + red[2] + red[3]) * (1.0f / DD) + 1e-5f);
  const float4 wv = reinterpret_cast<const float4*>(w)[t];
  ushort4 o;
  o.x = f2b(v.x * inv * wv.x);
  o.y = f2b(v.y * inv * wv.y);
  o.z = f2b(v.z * inv * wv.z);
  o.w = f2b(v.w * inv * wv.w);
  reinterpret_cast<ushort4*>(out + (size_t)row * DD)[t] = o;
}

// ---------------- MFMA GEMM: C[M,N] = A[M,K](bf16) @ Wb[N,K](bf16)^T ----------------
// m97 structure: BMxBN tile, BK=32, one 64x64 quadrant per wave (4x4 of 16x16x32 MFMAs),
// global_load_lds width-16 staging into lane-linear LDS (row-major [rows][32], no pad).
// ACT: 1 = exact gelu. RES: 0 -> bf16 Cb; 1 -> Co(f32) = resid(f32) + acc + bias(f32, optional)
template<int BM, int BN, int ACT, int RES>
__global__ __launch_bounds__((BM/64)*(BN/64)*64)
void mfma_gemm(const u16* __restrict__ A, const u16* __restrict__ Wb,
               u16* __restrict__ Cb, const float* __restrict__ resid,
               float* __restrict__ Co, const float* __restrict__ bias,
               int N, int K) {
  constexpr int WCOLS = BN / 64;
  constexpr int NW = (BM / 64) * WCOLS;
  constexpr int NT = NW * 64;
  constexpr int CA = BM * 4;        // 16B chunks in A tile (BM x 32 bf16)
  constexpr int CB = BN * 4;
  constexpr int IA = CA / NT, IB = CB / NT;
  __shared__ u16 As[BM * 32];
  __shared__ u16 Bs[BN * 32];
  const int t = threadIdx.x;
  const int lane = t & 63, w = t >> 6;
  const int wm = (w / WCOLS) * 64, wn = (w % WCOLS) * 64;
  const int m0 = blockIdx.y * BM, n0 = blockIdx.x * BN;
  const int fr = lane & 15, fq = lane >> 4;

  f32x4 acc[4][4] = {};

  for (int kt = 0; kt < K; kt += 32) {
    #pragma unroll
    for (int i = 0; i < IA; i++) {
      const int c = i * NT + t;
      gl2lds16(A + (size_t)(m0 + (c >> 2)) * K + kt + (c & 3) * 8, &As[c * 8]);
    }
    #pragma unroll
    for (int i = 0; i < IB; i++) {
      const int c = i * NT + t;
      gl2lds16(Wb + (size_t)(n0 + (c >> 2)) * K + kt + (c & 3) * 8, &Bs[c * 8]);
    }
    __syncthreads();   // vmcnt drained at barrier -> LDS tiles complete
    bf16x8 af[4], bfv[4];
    #pragma unroll
    for (int i = 0; i < 4; i++)
      af[i] = *reinterpret_cast<const bf16x8*>(&As[(wm + i * 16 + fr) * 32 + fq * 8]);
    #pragma unroll
    for (int j = 0; j < 4; j++)
      bfv[j] = *reinterpret_cast<const bf16x8*>(&Bs[(wn + j * 16 + fr) * 32 + fq * 8]);
    #pragma unroll
    for (int i = 0; i < 4; i++)
      #pragma unroll
      for (int j = 0; j < 4; j++)
        acc[i][j] = __builtin_amdgcn_mfma_f32_16x16x32_bf16(af[i], bfv[j], acc[i][j], 0, 0, 0);
    __syncthreads();   // all waves done reading before next tile's DMA overwrites
  }

  #pragma unroll
  for (int i = 0; i < 4; i++) {
    #pragma unroll
    for (int j = 0; j < 4; j++) {
      #pragma unroll
      for (int r = 0; r < 4; r++) {
        const int row = m0 + wm + i * 16 + fq * 4 + r;
        const int col = n0 + wn + j * 16 + fr;
        float val = acc[i][j][r];
        if (RES == 0) {
          if (ACT == 1) val = gelu_exact(val);
          Cb[(size_t)row * N + col] = f2b(val);
        } else {
          const float rv = resid[(size_t)row * N + col];
          const float bv = (bias != nullptr) ? bias[col] : 0.0f;
          Co[(size_t)row * N + col] = rv + val + bv;
        }
      }
    }
  }
}

// ---------------- causal linear attention (VALU, unchanged math) ----------------
// QKV fused layout: row stride QS=3072, Q at col 0, K at 1024, V at 2048; head h at +h*64
__global__ __launch_bounds__(256) void attn_kernel(const u16* __restrict__ QKV,
                                                   u16* __restrict__ O) {
  __shared__ float Qs[64][64], Ks[64][64], Ss[64][64];  // rotation-swizzled cols
  __shared__ u16 Vs[64][68];                            // plain, padded
  const int qt = blockIdx.x, h = blockIdx.y, b = blockIdx.z;
  const int t = threadIdx.x;
  const int tx = t & 15, ty = t >> 4;
  const int r0 = ty * 4, c0 = tx * 4;
  const int lrow = t >> 2, le0 = (t & 3) * 16;

  {  // load Q tile once
    const u16* qp = QKV + ((size_t)(b * LL + qt * 64 + lrow) * QS + h * HD + le0);
    union { uint4 u[2]; u16 s[16]; } pk;
    pk.u[0] = reinterpret_cast<const uint4*>(qp)[0];
    pk.u[1] = reinterpret_cast<const uint4*>(qp)[1];
    #pragma unroll
    for (int j = 0; j < 16; j++) Qs[lrow][(le0 + j + lrow) & 63] = b2f(pk.s[j]);
  }

  float acc[4][4] = {};
  for (int jt = 0; jt <= qt; jt++) {
    __syncthreads();
    {
      const u16* kp = QKV + ((size_t)(b * LL + jt * 64 + lrow) * QS + 1024 + h * HD + le0);
      const u16* vp = QKV + ((size_t)(b * LL + jt * 64 + lrow) * QS + 2048 + h * HD + le0);
      union { uint4 u[2]; u16 s[16]; } ku, vu;
      ku.u[0] = reinterpret_cast<const uint4*>(kp)[0];
      ku.u[1] = reinterpret_cast<const uint4*>(kp)[1];
      vu.u[0] = reinterpret_cast<const uint4*>(vp)[0];
      vu.u[1] = reinterpret_cast<const uint4*>(vp)[1];
      #pragma unroll
      for (int j = 0; j < 16; j++) Ks[lrow][(le0 + j + lrow) & 63] = b2f(ku.s[j]);
      #pragma unroll
      for (int j = 0; j < 4; j++) {
        ushort4 pv; pv.x = vu.s[j*4+0]; pv.y = vu.s[j*4+1]; pv.z = vu.s[j*4+2]; pv.w = vu.s[j*4+3];
        *reinterpret_cast<ushort4*>(&Vs[lrow][le0 + j * 4]) = pv;
      }
    }
    __syncthreads();
    float sacc[4][4] = {};
    #pragma unroll 4
    for (int kk = 0; kk < 64; kk++) {
      float ar[4], br[4];
      #pragma unroll
      for (int i = 0; i < 4; i++) ar[i] = Qs[r0 + i][(kk + r0 + i) & 63];
      #pragma unroll
      for (int j = 0; j < 4; j++) br[j] = Ks[c0 + j][(kk + c0 + j) & 63];
      #pragma unroll
      for (int i = 0; i < 4; i++)
        #pragma unroll
        for (int j = 0; j < 4; j++)
          sacc[i][j] += ar[i] * br[j];
    }
    const bool diag = (jt == qt);
    #pragma unroll
    for (int i = 0; i < 4; i++)
      #pragma unroll
      for (int j = 0; j < 4; j++) {
        float sv = sacc[i][j];
        if (diag && (c0 + j > r0 + i)) sv = 0.0f;  // causal inclusive
        Ss[r0 + i][(c0 + j + r0 + i) & 63] = sv;
      }
    __syncthreads();
    #pragma unroll 4
    for (int c = 0; c < 64; c++) {
      float sr[4], vr[4];
      #pragma unroll
      for (int i = 0; i < 4; i++) sr[i] = Ss[r0 + i][(c + r0 + i) & 63];
      const ushort4 pv = *reinterpret_cast<const ushort4*>(&Vs[c][c0]);
      vr[0] = b2f(pv.x); vr[1] = b2f(pv.y); vr[2] = b2f(pv.z); vr[3] = b2f(pv.w);
      #pragma unroll
      for (int i = 0; i < 4; i++)
        #pragma unroll
        for (int j = 0; j < 4; j++)
          acc[i][j] += sr[i] * vr[j];
    }
  }

  #pragma unroll
  for (int i = 0; i < 4; i++) {
    ushort4 pk;
    pk.x = f2b(acc[i][0]); pk.y = f2b(acc[i][1]);
    pk.z = f2b(acc[i][2]); pk.w = f2b(acc[i][3]);
    *reinterpret_cast<ushort4*>(O + ((size_t)(b * LL + qt * 64 + r0 + i) * DD + h * HD + c0)) = pk;
  }
}

// ---------------- host ----------------
// ws map (28 MB): wbuf bf16 0..8MB | h/a/m bf16 8..12MB | qkv bf16 12..24MB | f bf16 12..28MB
// fp32 residual stream lives in d_out (read-once-write-once in-place epilogues).
extern "C" void kernel_launch(void* const* d_in, const int* in_sizes, int n_in,
                              void* d_out, int out_size, void* d_ws, size_t ws_size,
                              hipStream_t stream) {
  const float* x_in = (const float*)d_in[0];
  const float* qw   = (const float*)d_in[1];
  const float* kw   = (const float*)d_in[2];
  const float* vw   = (const float*)d_in[3];
  const float* ow   = (const float*)d_in[4];
  const float* pn   = (const float*)d_in[5];
  const float* ln   = (const float*)d_in[6];
  const float* fcw  = (const float*)d_in[7];
  const float* fc2w = (const float*)d_in[8];
  const float* fc2b = (const float*)d_in[9];

  char* ws = (char*)d_ws;
  u16* wbuf = (u16*)ws;                        // 0..8MB rotating bf16 weights
  u16* h    = (u16*)(ws + (size_t)(8 << 20));  // 8..12MB (also a, m)
  u16* qkv  = (u16*)(ws + (size_t)(12 << 20)); // 12..24MB
  u16* f    = (u16*)(ws + (size_t)(12 << 20)); // 12..28MB (qkv dead by FC1)
  float* xf = (float*)d_out;                   // fp32 residual stream

  const int n8D = DD * DD / 8;       // 131072 -> grid 512
  const int n8F = DFFN * DD / 8;     // 524288 -> grid 2048

  for (int i = 0; i < 2; i++) {
    const float* qwi  = qw   + (size_t)i * DD * DD;
    const float* kwi  = kw   + (size_t)i * DD * DD;
    const float* vwi  = vw   + (size_t)i * DD * DD;
    const float* owi  = ow   + (size_t)i * DD * DD;
    const float* fcwi = fcw  + (size_t)i * DFFN * DD;
    const float* f2wi = fc2w + (size_t)i * DD * DFFN;
    const float* src  = (i == 0) ? x_in : xf;

    rmsnorm_kernel<<<MM, 256, 0, stream>>>(src, pn + i * DD, h);
    // fused QKV weights -> wbuf[3072][1024]
    castw_kernel<<<n8D / 256, 256, 0, stream>>>(qwi, wbuf,               n8D);
    castw_kernel<<<n8D / 256, 256, 0, stream>>>(kwi, wbuf + DD * DD,     n8D);
    castw_kernel<<<n8D / 256, 256, 0, stream>>>(vwi, wbuf + 2 * DD * DD, n8D);
    mfma_gemm<128, 128, 0, 0><<<dim3(QS / 128, MM / 128), 256, 0, stream>>>(
        h, wbuf, qkv, nullptr, nullptr, nullptr, QS, DD);
    attn_kernel<<<dim3(LL / 64, HH, BB), 256, 0, stream>>>(qkv, h /*a*/);
    castw_kernel<<<n8D / 256, 256, 0, stream>>>(owi, wbuf, n8D);
    mfma_gemm<64, 128, 0, 1><<<dim3(DD / 128, MM / 64), 128, 0, stream>>>(
        h /*a*/, wbuf, nullptr, src, xf, nullptr, DD, DD);
    rmsnorm_kernel<<<MM, 256, 0, stream>>>(xf, ln + i * DD, h /*m*/);
    castw_kernel<<<n8F / 256, 256, 0, stream>>>(fcwi, wbuf, n8F);
    mfma_gemm<128, 128, 1, 0><<<dim3(DFFN / 128, MM / 128), 256, 0, stream>>>(
        h /*m*/, wbuf, f, nullptr, nullptr, nullptr, DFFN, DD);
    castw_kernel<<<n8F / 256, 256, 0, stream>>>(f2wi, wbuf, n8F);
    mfma_gemm<64, 128, 0, 1><<<dim3(DD / 128, MM / 64), 128, 0, stream>>>(
        f, wbuf, nullptr, xf, xf, fc2b + i * DD, DD, DFFN);
  }
}

// Round 4
// 607.143 us; speedup vs baseline: 4.2025x; 1.5675x over previous
//
#include <hip/hip_runtime.h>

// Problem dims (fixed)
#define BB 2
#define LL 1024
#define DD 1024
#define HH 16
#define HD 64
#define DFFN 4096
#define MM (BB*LL)   // 2048 rows
#define QS 3072      // fused QKV row stride

using u16 = unsigned short;
typedef __bf16 bf16x8 __attribute__((ext_vector_type(8)));
typedef float f32x4 __attribute__((ext_vector_type(4)));

__device__ __forceinline__ float b2f(u16 u) {
  union { unsigned int i; float f; } v; v.i = ((unsigned int)u) << 16; return v.f;
}
__device__ __forceinline__ u16 f2b(float f) {
  union { float f; unsigned int i; } v; v.f = f;
  unsigned int x = v.i;
  return (u16)((x + 0x7fffu + ((x >> 16) & 1u)) >> 16);  // RNE, finite values
}
__device__ __forceinline__ float gelu_exact(float x) {
  return 0.5f * x * (1.0f + erff(x * 0.70710678118654752f));
}
__device__ __forceinline__ void gl2lds16(const void* g, void* l) {
  __builtin_amdgcn_global_load_lds((const __attribute__((address_space(1))) void*)g,
                                   (__attribute__((address_space(3))) void*)l, 16, 0, 0);
}

// ---------------- weight cast fp32 -> bf16, 8 elems/thread ----------------
__global__ __launch_bounds__(256) void castw_kernel(const float* __restrict__ in,
                                                    u16* __restrict__ out, int n8) {
  int i = blockIdx.x * 256 + threadIdx.x;
  if (i >= n8) return;
  const float4 a = reinterpret_cast<const float4*>(in)[2 * i];
  const float4 b = reinterpret_cast<const float4*>(in)[2 * i + 1];
  uint4 o;
  o.x = (unsigned)f2b(a.x) | ((unsigned)f2b(a.y) << 16);
  o.y = (unsigned)f2b(a.z) | ((unsigned)f2b(a.w) << 16);
  o.z = (unsigned)f2b(b.x) | ((unsigned)f2b(b.y) << 16);
  o.w = (unsigned)f2b(b.z) | ((unsigned)f2b(b.w) << 16);
  reinterpret_cast<uint4*>(out)[i] = o;
}

// ---------------- rmsnorm (fp32 in, fp32 weight, bf16 out) ----------------
__global__ __launch_bounds__(256) void rmsnorm_kernel(const float* __restrict__ x,
                                                      const float* __restrict__ w,
                                                      u16* __restrict__ out) {
  const int row = blockIdx.x, t = threadIdx.x;
  const float4 v = reinterpret_cast<const float4*>(x + (size_t)row * DD)[t];
  float ss = v.x*v.x + v.y*v.y + v.z*v.z + v.w*v.w;
  #pragma unroll
  for (int o = 32; o > 0; o >>= 1) ss += __shfl_down(ss, o);
  __shared__ float red[4];
  if ((t & 63) == 0) red[t >> 6] = ss;
  __syncthreads();
  const float inv = rsqrtf((red[0] + red[1] + red[2] + red[3]) * (1.0f / DD) + 1e-5f);
  const float4 wv = reinterpret_cast<const float4*>(w)[t];
  ushort4 o;
  o.x = f2b(v.x * inv * wv.x);
  o.y = f2b(v.y * inv * wv.y);
  o.z = f2b(v.z * inv * wv.z);
  o.w = f2b(v.w * inv * wv.w);
  reinterpret_cast<ushort4*>(out + (size_t)row * DD)[t] = o;
}

// ---------------- MFMA GEMM: C[M,N] = A[M,K](bf16) @ Wb[N,K](bf16)^T ----------------
template<int BM, int BN, int ACT, int RES>
__global__ __launch_bounds__((BM/64)*(BN/64)*64)
void mfma_gemm(const u16* __restrict__ A, const u16* __restrict__ Wb,
               u16* __restrict__ Cb, const float* __restrict__ resid,
               float* __restrict__ Co, const float* __restrict__ bias,
               int N, int K) {
  constexpr int WCOLS = BN / 64;
  constexpr int NW = (BM / 64) * WCOLS;
  constexpr int NT = NW * 64;
  constexpr int CA = BM * 4;
  constexpr int CB = BN * 4;
  constexpr int IA = CA / NT, IB = CB / NT;
  __shared__ u16 As[BM * 32];
  __shared__ u16 Bs[BN * 32];
  const int t = threadIdx.x;
  const int lane = t & 63, w = t >> 6;
  const int wm = (w / WCOLS) * 64, wn = (w % WCOLS) * 64;
  const int m0 = blockIdx.y * BM, n0 = blockIdx.x * BN;
  const int fr = lane & 15, fq = lane >> 4;

  f32x4 acc[4][4] = {};

  for (int kt = 0; kt < K; kt += 32) {
    #pragma unroll
    for (int i = 0; i < IA; i++) {
      const int c = i * NT + t;
      gl2lds16(A + (size_t)(m0 + (c >> 2)) * K + kt + (c & 3) * 8, &As[c * 8]);
    }
    #pragma unroll
    for (int i = 0; i < IB; i++) {
      const int c = i * NT + t;
      gl2lds16(Wb + (size_t)(n0 + (c >> 2)) * K + kt + (c & 3) * 8, &Bs[c * 8]);
    }
    __syncthreads();
    bf16x8 af[4], bfv[4];
    #pragma unroll
    for (int i = 0; i < 4; i++)
      af[i] = *reinterpret_cast<const bf16x8*>(&As[(wm + i * 16 + fr) * 32 + fq * 8]);
    #pragma unroll
    for (int j = 0; j < 4; j++)
      bfv[j] = *reinterpret_cast<const bf16x8*>(&Bs[(wn + j * 16 + fr) * 32 + fq * 8]);
    #pragma unroll
    for (int i = 0; i < 4; i++)
      #pragma unroll
      for (int j = 0; j < 4; j++)
        acc[i][j] = __builtin_amdgcn_mfma_f32_16x16x32_bf16(af[i], bfv[j], acc[i][j], 0, 0, 0);
    __syncthreads();
  }

  #pragma unroll
  for (int i = 0; i < 4; i++) {
    #pragma unroll
    for (int j = 0; j < 4; j++) {
      #pragma unroll
      for (int r = 0; r < 4; r++) {
        const int row = m0 + wm + i * 16 + fq * 4 + r;
        const int col = n0 + wn + j * 16 + fr;
        float val = acc[i][j][r];
        if (RES == 0) {
          if (ACT == 1) val = gelu_exact(val);
          Cb[(size_t)row * N + col] = f2b(val);
        } else {
          const float rv = resid[(size_t)row * N + col];
          const float bv = (bias != nullptr) ? bias[col] : 0.0f;
          Co[(size_t)row * N + col] = rv + val + bv;
        }
      }
    }
  }
}

// ---------------- K/V transpose: Kt/Vt[(b,h)][d][pos] <- qkv[b*L+pos][1024*(1+which)+h*64+d] ----
__global__ __launch_bounds__(256) void kv_trans(const u16* __restrict__ QKV,
                                                u16* __restrict__ Kt, u16* __restrict__ Vt) {
  const int tile = blockIdx.x;           // 16
  const int h2 = blockIdx.y;             // 32: h = h2&15, which = h2>>4 (0=K, 1=V)
  const int b = blockIdx.z;
  const int h = h2 & 15, which = h2 >> 4;
  const int t = threadIdx.x;
  const int pos = tile * 64 + (t >> 2), d0 = (t & 3) * 16;
  const u16* src = QKV + ((size_t)(b * LL) + pos) * QS + 1024 + which * 1024 + h * HD + d0;
  union { uint4 u[2]; u16 s[16]; } pk;
  pk.u[0] = reinterpret_cast<const uint4*>(src)[0];
  pk.u[1] = reinterpret_cast<const uint4*>(src)[1];
  u16* dst = (which ? Vt : Kt) + ((size_t)(b * HH + h) * HD + d0) * LL + pos;
  #pragma unroll
  for (int j = 0; j < 16; j++) dst[(size_t)j * LL] = pk.s[j];
}

// ---------------- attention phase 1: per (tile,h,b) ----------------
// S = Q K^T (causal-masked, intra-tile); O_intra = S V -> Oa; Slt = V^T K -> Slt buffer
// wave w owns q-rows (for S/O) and dv-rows (for Slt) [16w,16w+16)
__global__ __launch_bounds__(256) void attn_phase1(const u16* __restrict__ QKV,
                                                   const u16* __restrict__ Kt,
                                                   const u16* __restrict__ Vt,
                                                   u16* __restrict__ Oa,
                                                   u16* __restrict__ Slt) {
  __shared__ u16 Ss[4][16][64];
  const int tile = blockIdx.x, h = blockIdx.y, b = blockIdx.z;
  const int t = threadIdx.x, lane = t & 63, w = t >> 6;
  const int fr = lane & 15, fq = lane >> 4;
  const size_t tok0 = (size_t)(b * LL + tile * 64);
  const size_t bh = (size_t)(b * HH + h);
  const u16* Qb  = QKV + tok0 * QS + h * HD;
  const u16* Kb  = Qb + 1024;
  const u16* Ktb = Kt + bh * (HD * LL) + tile * 64;
  const u16* Vtb = Vt + bh * (HD * LL) + tile * 64;

  // ---- S = Q K^T ----
  bf16x8 aq[2], bk[4][2];
  #pragma unroll
  for (int kh = 0; kh < 2; kh++)
    aq[kh] = *reinterpret_cast<const bf16x8*>(Qb + (size_t)(16*w + fr) * QS + kh*32 + fq*8);
  #pragma unroll
  for (int n4 = 0; n4 < 4; n4++)
    #pragma unroll
    for (int kh = 0; kh < 2; kh++)
      bk[n4][kh] = *reinterpret_cast<const bf16x8*>(Kb + (size_t)(16*n4 + fr) * QS + kh*32 + fq*8);
  f32x4 sacc[4] = {};
  #pragma unroll
  for (int n4 = 0; n4 < 4; n4++) {
    sacc[n4] = __builtin_amdgcn_mfma_f32_16x16x32_bf16(aq[0], bk[n4][0], sacc[n4], 0, 0, 0);
    sacc[n4] = __builtin_amdgcn_mfma_f32_16x16x32_bf16(aq[1], bk[n4][1], sacc[n4], 0, 0, 0);
  }
  // causal mask (inclusive) + bf16 -> LDS (C layout: row=4fq+r, col=16n4+fr)
  #pragma unroll
  for (int n4 = 0; n4 < 4; n4++)
    #pragma unroll
    for (int r = 0; r < 4; r++) {
      const bool keep = (16*w + 4*fq + r) >= (16*n4 + fr);
      Ss[w][4*fq + r][16*n4 + fr] = keep ? f2b(sacc[n4][r]) : (u16)0;
    }
  __syncthreads();

  // ---- Slt = V^T K  (rows dv, cols dk) ----
  bf16x8 va[2], kt[4][2];
  #pragma unroll
  for (int kh = 0; kh < 2; kh++)
    va[kh] = *reinterpret_cast<const bf16x8*>(Vtb + (size_t)(16*w + fr) * LL + kh*32 + fq*8);
  #pragma unroll
  for (int n4 = 0; n4 < 4; n4++)
    #pragma unroll
    for (int kh = 0; kh < 2; kh++)
      kt[n4][kh] = *reinterpret_cast<const bf16x8*>(Ktb + (size_t)(16*n4 + fr) * LL + kh*32 + fq*8);
  f32x4 lacc[4] = {};
  #pragma unroll
  for (int n4 = 0; n4 < 4; n4++) {
    lacc[n4] = __builtin_amdgcn_mfma_f32_16x16x32_bf16(va[0], kt[n4][0], lacc[n4], 0, 0, 0);
    lacc[n4] = __builtin_amdgcn_mfma_f32_16x16x32_bf16(va[1], kt[n4][1], lacc[n4], 0, 0, 0);
  }
  u16* So = Slt + (bh * 16 + tile) * 4096;
  #pragma unroll
  for (int n4 = 0; n4 < 4; n4++)
    #pragma unroll
    for (int r = 0; r < 4; r++)
      So[(size_t)(16*w + 4*fq + r) * 64 + 16*n4 + fr] = f2b(lacc[n4][r]);

  // ---- O_intra = S V ----
  bf16x8 sa[2], vb[4][2];
  #pragma unroll
  for (int kh = 0; kh < 2; kh++)
    sa[kh] = *reinterpret_cast<const bf16x8*>(&Ss[w][fr][kh*32 + fq*8]);
  #pragma unroll
  for (int n4 = 0; n4 < 4; n4++)
    #pragma unroll
    for (int kh = 0; kh < 2; kh++)
      vb[n4][kh] = *reinterpret_cast<const bf16x8*>(Vtb + (size_t)(16*n4 + fr) * LL + kh*32 + fq*8);
  f32x4 oacc[4] = {};
  #pragma unroll
  for (int n4 = 0; n4 < 4; n4++) {
    oacc[n4] = __builtin_amdgcn_mfma_f32_16x16x32_bf16(sa[0], vb[n4][0], oacc[n4], 0, 0, 0);
    oacc[n4] = __builtin_amdgcn_mfma_f32_16x16x32_bf16(sa[1], vb[n4][1], oacc[n4], 0, 0, 0);
  }
  u16* Ob = Oa + (tok0 + 16*w) * DD + h * HD;
  #pragma unroll
  for (int n4 = 0; n4 < 4; n4++)
    #pragma unroll
    for (int r = 0; r < 4; r++)
      Ob[(size_t)(4*fq + r) * DD + 16*n4 + fr] = f2b(oacc[n4][r]);
}

// ---------------- attention phase 2: exclusive fp32 scan of Slt tiles -> Wcum (bf16) ----------
// grid (8, HH, BB): each block scans an 8-row slab (8x64=512 elems, 2/thread) over 16 tiles
__global__ __launch_bounds__(256) void attn_phase2(const u16* __restrict__ Slt,
                                                   u16* __restrict__ Wc) {
  const int rg = blockIdx.x, h = blockIdx.y, b = blockIdx.z;
  const size_t base = ((size_t)((b * HH + h) * 16)) * 4096 + rg * 512 + threadIdx.x * 2;
  float r0 = 0.f, r1 = 0.f;
  for (int tl = 0; tl < 16; tl++) {
    const size_t p = base + (size_t)tl * 4096;
    const unsigned d = *reinterpret_cast<const unsigned*>(Slt + p);
    *reinterpret_cast<unsigned*>(Wc + p) = (unsigned)f2b(r0) | ((unsigned)f2b(r1) << 16);
    r0 += b2f((u16)(d & 0xffff));
    r1 += b2f((u16)(d >> 16));
  }
}

// ---------------- attention phase 3: O += Q @ W_prev ----------------
// Wc rows are Wt[dv][dk] = W^T -> exactly the B-operand layout for Q @ W
__global__ __launch_bounds__(256) void attn_phase3(const u16* __restrict__ QKV,
                                                   const u16* __restrict__ Wc,
                                                   u16* __restrict__ Oa) {
  const int tile = blockIdx.x, h = blockIdx.y, b = blockIdx.z;
  const int t = threadIdx.x, lane = t & 63, w = t >> 6;
  const int fr = lane & 15, fq = lane >> 4;
  const size_t tok0 = (size_t)(b * LL + tile * 64);
  const size_t bh = (size_t)(b * HH + h);
  const u16* Qb = QKV + tok0 * QS + h * HD;
  const u16* Wb = Wc + (bh * 16 + tile) * 4096;

  bf16x8 aq[2], wb[4][2];
  #pragma unroll
  for (int kh = 0; kh < 2; kh++)
    aq[kh] = *reinterpret_cast<const bf16x8*>(Qb + (size_t)(16*w + fr) * QS + kh*32 + fq*8);
  #pragma unroll
  for (int n4 = 0; n4 < 4; n4++)
    #pragma unroll
    for (int kh = 0; kh < 2; kh++)
      wb[n4][kh] = *reinterpret_cast<const bf16x8*>(Wb + (size_t)(16*n4 + fr) * 64 + kh*32 + fq*8);
  f32x4 oacc[4] = {};
  #pragma unroll
  for (int n4 = 0; n4 < 4; n4++) {
    oacc[n4] = __builtin_amdgcn_mfma_f32_16x16x32_bf16(aq[0], wb[n4][0], oacc[n4], 0, 0, 0);
    oacc[n4] = __builtin_amdgcn_mfma_f32_16x16x32_bf16(aq[1], wb[n4][1], oacc[n4], 0, 0, 0);
  }
  u16* Ob = Oa + (tok0 + 16*w) * DD + h * HD;
  #pragma unroll
  for (int n4 = 0; n4 < 4; n4++)
    #pragma unroll
    for (int r = 0; r < 4; r++) {
      const size_t idx = (size_t)(4*fq + r) * DD + 16*n4 + fr;
      Ob[idx] = f2b(b2f(Ob[idx]) + oacc[n4][r]);
    }
}

// ---------------- host ----------------
// ws map (32 MB): wbuf 0..8 (weights; time-shared with Slt 0..4 / Wcum 4..8 during attn)
// h/a/m 8..12 | qkv 12..24 | f 12..28 (after attn) | Vt 24..28 | Kt 28..32
extern "C" void kernel_launch(void* const* d_in, const int* in_sizes, int n_in,
                              void* d_out, int out_size, void* d_ws, size_t ws_size,
                              hipStream_t stream) {
  const float* x_in = (const float*)d_in[0];
  const float* qw   = (const float*)d_in[1];
  const float* kw   = (const float*)d_in[2];
  const float* vw   = (const float*)d_in[3];
  const float* ow   = (const float*)d_in[4];
  const float* pn   = (const float*)d_in[5];
  const float* ln   = (const float*)d_in[6];
  const float* fcw  = (const float*)d_in[7];
  const float* fc2w = (const float*)d_in[8];
  const float* fc2b = (const float*)d_in[9];

  char* ws = (char*)d_ws;
  u16* wbuf = (u16*)ws;                         // 0..8MB rotating bf16 weights
  u16* slt  = (u16*)ws;                         // 0..4MB (attn window)
  u16* wcum = (u16*)(ws + (size_t)(4 << 20));   // 4..8MB (attn window)
  u16* h    = (u16*)(ws + (size_t)(8 << 20));   // 8..12MB (also a, m)
  u16* qkv  = (u16*)(ws + (size_t)(12 << 20));  // 12..24MB
  u16* f    = (u16*)(ws + (size_t)(12 << 20));  // 12..28MB (qkv/Vt dead by FC1)
  u16* vt   = (u16*)(ws + (size_t)(24 << 20));  // 24..28MB
  u16* kt   = (u16*)(ws + (size_t)(28 << 20));  // 28..32MB
  float* xf = (float*)d_out;                    // fp32 residual stream

  const int n8D = DD * DD / 8;
  const int n8F = DFFN * DD / 8;

  for (int i = 0; i < 2; i++) {
    const float* qwi  = qw   + (size_t)i * DD * DD;
    const float* kwi  = kw   + (size_t)i * DD * DD;
    const float* vwi  = vw   + (size_t)i * DD * DD;
    const float* owi  = ow   + (size_t)i * DD * DD;
    const float* fcwi = fcw  + (size_t)i * DFFN * DD;
    const float* f2wi = fc2w + (size_t)i * DD * DFFN;
    const float* src  = (i == 0) ? x_in : xf;

    rmsnorm_kernel<<<MM, 256, 0, stream>>>(src, pn + i * DD, h);
    castw_kernel<<<n8D / 256, 256, 0, stream>>>(qwi, wbuf,               n8D);
    castw_kernel<<<n8D / 256, 256, 0, stream>>>(kwi, wbuf + DD * DD,     n8D);
    castw_kernel<<<n8D / 256, 256, 0, stream>>>(vwi, wbuf + 2 * DD * DD, n8D);
    mfma_gemm<128, 128, 0, 0><<<dim3(QS / 128, MM / 128), 256, 0, stream>>>(
        h, wbuf, qkv, nullptr, nullptr, nullptr, QS, DD);
    // chunked linear attention (a = h region)
    kv_trans<<<dim3(16, 32, BB), 256, 0, stream>>>(qkv, kt, vt);
    attn_phase1<<<dim3(16, HH, BB), 256, 0, stream>>>(qkv, kt, vt, h, slt);
    attn_phase2<<<dim3(8, HH, BB), 256, 0, stream>>>(slt, wcum);
    attn_phase3<<<dim3(16, HH, BB), 256, 0, stream>>>(qkv, wcum, h);
    castw_kernel<<<n8D / 256, 256, 0, stream>>>(owi, wbuf, n8D);
    mfma_gemm<64, 128, 0, 1><<<dim3(DD / 128, MM / 64), 128, 0, stream>>>(
        h, wbuf, nullptr, src, xf, nullptr, DD, DD);
    rmsnorm_kernel<<<MM, 256, 0, stream>>>(xf, ln + i * DD, h);
    castw_kernel<<<n8F / 256, 256, 0, stream>>>(fcwi, wbuf, n8F);
    mfma_gemm<128, 128, 1, 0><<<dim3(DFFN / 128, MM / 128), 256, 0, stream>>>(
        h, wbuf, f, nullptr, nullptr, nullptr, DFFN, DD);
    castw_kernel<<<n8F / 256, 256, 0, stream>>>(f2wi, wbuf, n8F);
    float* co = (i == 1) ? (float*)d_out : xf;
    mfma_gemm<64, 128, 0, 1><<<dim3(DD / 128, MM / 64), 128, 0, stream>>>(
        f, wbuf, nullptr, xf, co, fc2b + i * DD, DD, DFFN);
  }
}

// Round 5
// 547.025 us; speedup vs baseline: 4.6644x; 1.1099x over previous
//
#include <hip/hip_runtime.h>

// Problem dims (fixed)
#define BB 2
#define LL 1024
#define DD 1024
#define HH 16
#define HD 64
#define DFFN 4096
#define MM (BB*LL)   // 2048 rows
#define QS 3072      // fused QKV row stride

using u16 = unsigned short;
typedef __bf16 bf16x8 __attribute__((ext_vector_type(8)));
typedef float f32x4 __attribute__((ext_vector_type(4)));

__device__ __forceinline__ float b2f(u16 u) {
  union { unsigned int i; float f; } v; v.i = ((unsigned int)u) << 16; return v.f;
}
__device__ __forceinline__ u16 f2b(float f) {
  union { float f; unsigned int i; } v; v.f = f;
  unsigned int x = v.i;
  return (u16)((x + 0x7fffu + ((x >> 16) & 1u)) >> 16);  // RNE, finite values
}
__device__ __forceinline__ float gelu_exact(float x) {
  return 0.5f * x * (1.0f + erff(x * 0.70710678118654752f));
}
__device__ __forceinline__ void gl2lds16(const void* g, void* l) {
  __builtin_amdgcn_global_load_lds((const __attribute__((address_space(1))) void*)g,
                                   (__attribute__((address_space(3))) void*)l, 16, 0, 0);
}

// ---------------- weight casts fp32 -> bf16 ----------------
__global__ __launch_bounds__(256) void castw_kernel(const float* __restrict__ in,
                                                    u16* __restrict__ out, int n8) {
  int i = blockIdx.x * 256 + threadIdx.x;
  if (i >= n8) return;
  const float4 a = reinterpret_cast<const float4*>(in)[2 * i];
  const float4 b = reinterpret_cast<const float4*>(in)[2 * i + 1];
  uint4 o;
  o.x = (unsigned)f2b(a.x) | ((unsigned)f2b(a.y) << 16);
  o.y = (unsigned)f2b(a.z) | ((unsigned)f2b(a.w) << 16);
  o.z = (unsigned)f2b(b.x) | ((unsigned)f2b(b.y) << 16);
  o.w = (unsigned)f2b(b.z) | ((unsigned)f2b(b.w) << 16);
  reinterpret_cast<uint4*>(out)[i] = o;
}
__global__ __launch_bounds__(256) void castw3_kernel(const float* __restrict__ s0,
                                                     const float* __restrict__ s1,
                                                     const float* __restrict__ s2,
                                                     u16* __restrict__ out, int n8) {
  int i = blockIdx.x * 256 + threadIdx.x;
  if (i >= n8) return;
  const float* in = (blockIdx.y == 0) ? s0 : (blockIdx.y == 1) ? s1 : s2;
  u16* dst = out + (size_t)blockIdx.y * n8 * 8;
  const float4 a = reinterpret_cast<const float4*>(in)[2 * i];
  const float4 b = reinterpret_cast<const float4*>(in)[2 * i + 1];
  uint4 o;
  o.x = (unsigned)f2b(a.x) | ((unsigned)f2b(a.y) << 16);
  o.y = (unsigned)f2b(a.z) | ((unsigned)f2b(a.w) << 16);
  o.z = (unsigned)f2b(b.x) | ((unsigned)f2b(b.y) << 16);
  o.w = (unsigned)f2b(b.z) | ((unsigned)f2b(b.w) << 16);
  reinterpret_cast<uint4*>(dst)[i] = o;
}

// ---------------- out = resid (+ bias), fp32 ----------------
__global__ __launch_bounds__(256) void init_out_kernel(float* __restrict__ out,
                                                       const float* __restrict__ resid,
                                                       const float* __restrict__ bias) {
  const int i = blockIdx.x * 256 + threadIdx.x;   // float4 index
  float4 v = reinterpret_cast<const float4*>(resid)[i];
  if (bias != nullptr) {
    const float4 bv = *reinterpret_cast<const float4*>(bias + ((i * 4) & (DD - 1)));
    v.x += bv.x; v.y += bv.y; v.z += bv.z; v.w += bv.w;
  }
  reinterpret_cast<float4*>(out)[i] = v;
}

// ---------------- rmsnorm (fp32 in, fp32 weight, bf16 out) ----------------
__global__ __launch_bounds__(256) void rmsnorm_kernel(const float* __restrict__ x,
                                                      const float* __restrict__ w,
                                                      u16* __restrict__ out) {
  const int row = blockIdx.x, t = threadIdx.x;
  const float4 v = reinterpret_cast<const float4*>(x + (size_t)row * DD)[t];
  float ss = v.x*v.x + v.y*v.y + v.z*v.z + v.w*v.w;
  #pragma unroll
  for (int o = 32; o > 0; o >>= 1) ss += __shfl_down(ss, o);
  __shared__ float red[4];
  if ((t & 63) == 0) red[t >> 6] = ss;
  __syncthreads();
  const float inv = rsqrtf((red[0] + red[1] + red[2] + red[3]) * (1.0f / DD) + 1e-5f);
  const float4 wv = reinterpret_cast<const float4*>(w)[t];
  ushort4 o;
  o.x = f2b(v.x * inv * wv.x);
  o.y = f2b(v.y * inv * wv.y);
  o.z = f2b(v.z * inv * wv.z);
  o.w = f2b(v.w * inv * wv.w);
  reinterpret_cast<ushort4*>(out + (size_t)row * DD)[t] = o;
}

// ---------------- MFMA GEMM (RES=0): C[M,N](bf16) = A @ Wb^T ----------------
template<int BM, int BN, int ACT>
__global__ __launch_bounds__((BM/64)*(BN/64)*64)
void mfma_gemm(const u16* __restrict__ A, const u16* __restrict__ Wb,
               u16* __restrict__ Cb, int N, int K) {
  constexpr int WCOLS = BN / 64;
  constexpr int NW = (BM / 64) * WCOLS;
  constexpr int NT = NW * 64;
  constexpr int IA = BM * 4 / NT, IB = BN * 4 / NT;
  __shared__ u16 As[BM * 32];
  __shared__ u16 Bs[BN * 32];
  const int t = threadIdx.x;
  const int lane = t & 63, w = t >> 6;
  const int wm = (w / WCOLS) * 64, wn = (w % WCOLS) * 64;
  const int m0 = blockIdx.y * BM, n0 = blockIdx.x * BN;
  const int fr = lane & 15, fq = lane >> 4;

  f32x4 acc[4][4] = {};
  for (int kt = 0; kt < K; kt += 32) {
    #pragma unroll
    for (int i = 0; i < IA; i++) {
      const int c = i * NT + t;
      gl2lds16(A + (size_t)(m0 + (c >> 2)) * K + kt + (c & 3) * 8, &As[c * 8]);
    }
    #pragma unroll
    for (int i = 0; i < IB; i++) {
      const int c = i * NT + t;
      gl2lds16(Wb + (size_t)(n0 + (c >> 2)) * K + kt + (c & 3) * 8, &Bs[c * 8]);
    }
    __syncthreads();
    bf16x8 af[4], bfv[4];
    #pragma unroll
    for (int i = 0; i < 4; i++)
      af[i] = *reinterpret_cast<const bf16x8*>(&As[(wm + i * 16 + fr) * 32 + fq * 8]);
    #pragma unroll
    for (int j = 0; j < 4; j++)
      bfv[j] = *reinterpret_cast<const bf16x8*>(&Bs[(wn + j * 16 + fr) * 32 + fq * 8]);
    #pragma unroll
    for (int i = 0; i < 4; i++)
      #pragma unroll
      for (int j = 0; j < 4; j++)
        acc[i][j] = __builtin_amdgcn_mfma_f32_16x16x32_bf16(af[i], bfv[j], acc[i][j], 0, 0, 0);
    __syncthreads();
  }

  #pragma unroll
  for (int i = 0; i < 4; i++)
    #pragma unroll
    for (int j = 0; j < 4; j++)
      #pragma unroll
      for (int r = 0; r < 4; r++) {
        const int row = m0 + wm + i * 16 + fq * 4 + r;
        const int col = n0 + wn + j * 16 + fr;
        float val = acc[i][j][r];
        if (ACT == 1) val = gelu_exact(val);
        Cb[(size_t)row * N + col] = f2b(val);
      }
}

// ---------------- split-K MFMA GEMM: Co(f32) += A @ Wb^T  (Co pre-initialized) ----------------
template<int SPLIT>
__global__ __launch_bounds__(256)
void mfma_gemm_sk(const u16* __restrict__ A, const u16* __restrict__ Wb,
                  float* __restrict__ Co, int N, int K) {
  constexpr int BM = 128, BN = 128;
  __shared__ u16 As[BM * 32];
  __shared__ u16 Bs[BN * 32];
  const int t = threadIdx.x;
  const int lane = t & 63, w = t >> 6;
  const int wm = (w >> 1) * 64, wn = (w & 1) * 64;
  const int m0 = blockIdx.y * BM, n0 = blockIdx.x * BN;
  const int fr = lane & 15, fq = lane >> 4;
  const int Kc = K / SPLIT, k0 = blockIdx.z * Kc;

  f32x4 acc[4][4] = {};
  for (int kt = k0; kt < k0 + Kc; kt += 32) {
    #pragma unroll
    for (int i = 0; i < 2; i++) {
      const int c = i * 256 + t;
      gl2lds16(A + (size_t)(m0 + (c >> 2)) * K + kt + (c & 3) * 8, &As[c * 8]);
      gl2lds16(Wb + (size_t)(n0 + (c >> 2)) * K + kt + (c & 3) * 8, &Bs[c * 8]);
    }
    __syncthreads();
    bf16x8 af[4], bfv[4];
    #pragma unroll
    for (int i = 0; i < 4; i++)
      af[i] = *reinterpret_cast<const bf16x8*>(&As[(wm + i * 16 + fr) * 32 + fq * 8]);
    #pragma unroll
    for (int j = 0; j < 4; j++)
      bfv[j] = *reinterpret_cast<const bf16x8*>(&Bs[(wn + j * 16 + fr) * 32 + fq * 8]);
    #pragma unroll
    for (int i = 0; i < 4; i++)
      #pragma unroll
      for (int j = 0; j < 4; j++)
        acc[i][j] = __builtin_amdgcn_mfma_f32_16x16x32_bf16(af[i], bfv[j], acc[i][j], 0, 0, 0);
    __syncthreads();
  }

  #pragma unroll
  for (int i = 0; i < 4; i++)
    #pragma unroll
    for (int j = 0; j < 4; j++)
      #pragma unroll
      for (int r = 0; r < 4; r++) {
        const int row = m0 + wm + i * 16 + fq * 4 + r;
        const int col = n0 + wn + j * 16 + fr;
        unsafeAtomicAdd(&Co[(size_t)row * N + col], acc[i][j][r]);
      }
}

// ---------------- K/V transpose via LDS, coalesced both sides ----------------
__global__ __launch_bounds__(256) void kv_trans(const u16* __restrict__ QKV,
                                                u16* __restrict__ Kt, u16* __restrict__ Vt) {
  __shared__ u16 T[64][72];
  const int tile = blockIdx.x;           // 16
  const int h2 = blockIdx.y;             // 32: h = h2&15, which = h2>>4 (0=K, 1=V)
  const int b = blockIdx.z;
  const int h = h2 & 15, which = h2 >> 4;
  const int t = threadIdx.x;
  const int pos = t >> 2, d0 = (t & 3) * 16;
  const u16* src = QKV + ((size_t)(b * LL) + tile * 64 + pos) * QS + 1024 + which * 1024 + h * HD + d0;
  union { uint4 u[2]; u16 s[16]; } pk;
  pk.u[0] = reinterpret_cast<const uint4*>(src)[0];
  pk.u[1] = reinterpret_cast<const uint4*>(src)[1];
  #pragma unroll
  for (int j = 0; j < 16; j++) T[d0 + j][pos] = pk.s[j];
  __syncthreads();
  const int d = t >> 2, p0 = (t & 3) * 16;
  u16* dst = (which ? Vt : Kt) + ((size_t)(b * HH + h) * HD + d) * LL + tile * 64 + p0;
  union { uint4 u[2]; u16 s[16]; } ok;
  #pragma unroll
  for (int j = 0; j < 16; j++) ok.s[j] = T[d][p0 + j];
  reinterpret_cast<uint4*>(dst)[0] = ok.u[0];
  reinterpret_cast<uint4*>(dst)[1] = ok.u[1];
}

// ---------------- attention phase 1 ----------------
__global__ __launch_bounds__(256) void attn_phase1(const u16* __restrict__ QKV,
                                                   const u16* __restrict__ Kt,
                                                   const u16* __restrict__ Vt,
                                                   u16* __restrict__ Oa,
                                                   u16* __restrict__ Slt) {
  __shared__ u16 Ss[4][16][64];
  const int tile = blockIdx.x, h = blockIdx.y, b = blockIdx.z;
  const int t = threadIdx.x, lane = t & 63, w = t >> 6;
  const int fr = lane & 15, fq = lane >> 4;
  const size_t tok0 = (size_t)(b * LL + tile * 64);
  const size_t bh = (size_t)(b * HH + h);
  const u16* Qb  = QKV + tok0 * QS + h * HD;
  const u16* Kb  = Qb + 1024;
  const u16* Ktb = Kt + bh * (HD * LL) + tile * 64;
  const u16* Vtb = Vt + bh * (HD * LL) + tile * 64;

  // ---- S = Q K^T ----
  bf16x8 aq[2], bk[4][2];
  #pragma unroll
  for (int kh = 0; kh < 2; kh++)
    aq[kh] = *reinterpret_cast<const bf16x8*>(Qb + (size_t)(16*w + fr) * QS + kh*32 + fq*8);
  #pragma unroll
  for (int n4 = 0; n4 < 4; n4++)
    #pragma unroll
    for (int kh = 0; kh < 2; kh++)
      bk[n4][kh] = *reinterpret_cast<const bf16x8*>(Kb + (size_t)(16*n4 + fr) * QS + kh*32 + fq*8);
  f32x4 sacc[4] = {};
  #pragma unroll
  for (int n4 = 0; n4 < 4; n4++) {
    sacc[n4] = __builtin_amdgcn_mfma_f32_16x16x32_bf16(aq[0], bk[n4][0], sacc[n4], 0, 0, 0);
    sacc[n4] = __builtin_amdgcn_mfma_f32_16x16x32_bf16(aq[1], bk[n4][1], sacc[n4], 0, 0, 0);
  }
  #pragma unroll
  for (int n4 = 0; n4 < 4; n4++)
    #pragma unroll
    for (int r = 0; r < 4; r++) {
      const bool keep = (16*w + 4*fq + r) >= (16*n4 + fr);
      Ss[w][4*fq + r][16*n4 + fr] = keep ? f2b(sacc[n4][r]) : (u16)0;
    }
  __syncthreads();

  // ---- Slt = V^T K ----
  bf16x8 va[2], kt[4][2];
  #pragma unroll
  for (int kh = 0; kh < 2; kh++)
    va[kh] = *reinterpret_cast<const bf16x8*>(Vtb + (size_t)(16*w + fr) * LL + kh*32 + fq*8);
  #pragma unroll
  for (int n4 = 0; n4 < 4; n4++)
    #pragma unroll
    for (int kh = 0; kh < 2; kh++)
      kt[n4][kh] = *reinterpret_cast<const bf16x8*>(Ktb + (size_t)(16*n4 + fr) * LL + kh*32 + fq*8);
  f32x4 lacc[4] = {};
  #pragma unroll
  for (int n4 = 0; n4 < 4; n4++) {
    lacc[n4] = __builtin_amdgcn_mfma_f32_16x16x32_bf16(va[0], kt[n4][0], lacc[n4], 0, 0, 0);
    lacc[n4] = __builtin_amdgcn_mfma_f32_16x16x32_bf16(va[1], kt[n4][1], lacc[n4], 0, 0, 0);
  }
  u16* So = Slt + (bh * 16 + tile) * 4096;
  #pragma unroll
  for (int n4 = 0; n4 < 4; n4++)
    #pragma unroll
    for (int r = 0; r < 4; r++)
      So[(size_t)(16*w + 4*fq + r) * 64 + 16*n4 + fr] = f2b(lacc[n4][r]);

  // ---- O_intra = S V ----
  bf16x8 sa[2], vb[4][2];
  #pragma unroll
  for (int kh = 0; kh < 2; kh++)
    sa[kh] = *reinterpret_cast<const bf16x8*>(&Ss[w][fr][kh*32 + fq*8]);
  #pragma unroll
  for (int n4 = 0; n4 < 4; n4++)
    #pragma unroll
    for (int kh = 0; kh < 2; kh++)
      vb[n4][kh] = *reinterpret_cast<const bf16x8*>(Vtb + (size_t)(16*n4 + fr) * LL + kh*32 + fq*8);
  f32x4 oacc[4] = {};
  #pragma unroll
  for (int n4 = 0; n4 < 4; n4++) {
    oacc[n4] = __builtin_amdgcn_mfma_f32_16x16x32_bf16(sa[0], vb[n4][0], oacc[n4], 0, 0, 0);
    oacc[n4] = __builtin_amdgcn_mfma_f32_16x16x32_bf16(sa[1], vb[n4][1], oacc[n4], 0, 0, 0);
  }
  u16* Ob = Oa + (tok0 + 16*w) * DD + h * HD;
  #pragma unroll
  for (int n4 = 0; n4 < 4; n4++)
    #pragma unroll
    for (int r = 0; r < 4; r++)
      Ob[(size_t)(4*fq + r) * DD + 16*n4 + fr] = f2b(oacc[n4][r]);
}

// ---------------- attention phase 2: exclusive fp32 scan ----------------
__global__ __launch_bounds__(256) void attn_phase2(const u16* __restrict__ Slt,
                                                   u16* __restrict__ Wc) {
  const int rg = blockIdx.x, h = blockIdx.y, b = blockIdx.z;
  const size_t base = ((size_t)((b * HH + h) * 16)) * 4096 + rg * 512 + threadIdx.x * 2;
  float r0 = 0.f, r1 = 0.f;
  for (int tl = 0; tl < 16; tl++) {
    const size_t p = base + (size_t)tl * 4096;
    const unsigned d = *reinterpret_cast<const unsigned*>(Slt + p);
    *reinterpret_cast<unsigned*>(Wc + p) = (unsigned)f2b(r0) | ((unsigned)f2b(r1) << 16);
    r0 += b2f((u16)(d & 0xffff));
    r1 += b2f((u16)(d >> 16));
  }
}

// ---------------- attention phase 3: O += Q @ W_prev ----------------
__global__ __launch_bounds__(256) void attn_phase3(const u16* __restrict__ QKV,
                                                   const u16* __restrict__ Wc,
                                                   u16* __restrict__ Oa) {
  const int tile = blockIdx.x, h = blockIdx.y, b = blockIdx.z;
  const int t = threadIdx.x, lane = t & 63, w = t >> 6;
  const int fr = lane & 15, fq = lane >> 4;
  const size_t tok0 = (size_t)(b * LL + tile * 64);
  const size_t bh = (size_t)(b * HH + h);
  const u16* Qb = QKV + tok0 * QS + h * HD;
  const u16* Wb = Wc + (bh * 16 + tile) * 4096;

  bf16x8 aq[2], wb[4][2];
  #pragma unroll
  for (int kh = 0; kh < 2; kh++)
    aq[kh] = *reinterpret_cast<const bf16x8*>(Qb + (size_t)(16*w + fr) * QS + kh*32 + fq*8);
  #pragma unroll
  for (int n4 = 0; n4 < 4; n4++)
    #pragma unroll
    for (int kh = 0; kh < 2; kh++)
      wb[n4][kh] = *reinterpret_cast<const bf16x8*>(Wb + (size_t)(16*n4 + fr) * 64 + kh*32 + fq*8);
  f32x4 oacc[4] = {};
  #pragma unroll
  for (int n4 = 0; n4 < 4; n4++) {
    oacc[n4] = __builtin_amdgcn_mfma_f32_16x16x32_bf16(aq[0], wb[n4][0], oacc[n4], 0, 0, 0);
    oacc[n4] = __builtin_amdgcn_mfma_f32_16x16x32_bf16(aq[1], wb[n4][1], oacc[n4], 0, 0, 0);
  }
  u16* Ob = Oa + (tok0 + 16*w) * DD + h * HD;
  #pragma unroll
  for (int n4 = 0; n4 < 4; n4++)
    #pragma unroll
    for (int r = 0; r < 4; r++) {
      const size_t idx = (size_t)(4*fq + r) * DD + 16*n4 + fr;
      Ob[idx] = f2b(b2f(Ob[idx]) + oacc[n4][r]);
    }
}

// ---------------- host ----------------
// ws map (32 MB): wbuf 0..8 (time-shared with Slt 0..4 / Wcum 4..8 during attn)
// h/a/m 8..12 | qkv 12..24 | f 12..28 (after attn) | Vt 24..28 | Kt 28..32
extern "C" void kernel_launch(void* const* d_in, const int* in_sizes, int n_in,
                              void* d_out, int out_size, void* d_ws, size_t ws_size,
                              hipStream_t stream) {
  const float* x_in = (const float*)d_in[0];
  const float* qw   = (const float*)d_in[1];
  const float* kw   = (const float*)d_in[2];
  const float* vw   = (const float*)d_in[3];
  const float* ow   = (const float*)d_in[4];
  const float* pn   = (const float*)d_in[5];
  const float* ln   = (const float*)d_in[6];
  const float* fcw  = (const float*)d_in[7];
  const float* fc2w = (const float*)d_in[8];
  const float* fc2b = (const float*)d_in[9];

  char* ws = (char*)d_ws;
  u16* wbuf = (u16*)ws;
  u16* slt  = (u16*)ws;
  u16* wcum = (u16*)(ws + (size_t)(4 << 20));
  u16* h    = (u16*)(ws + (size_t)(8 << 20));
  u16* qkv  = (u16*)(ws + (size_t)(12 << 20));
  u16* f    = (u16*)(ws + (size_t)(12 << 20));
  u16* vt   = (u16*)(ws + (size_t)(24 << 20));
  u16* kt   = (u16*)(ws + (size_t)(28 << 20));
  float* xf = (float*)d_out;

  const int n8D = DD * DD / 8;
  const int n8F = DFFN * DD / 8;
  const int gInit = MM * DD / 4 / 256;   // 2048

  for (int i = 0; i < 2; i++) {
    const float* qwi  = qw   + (size_t)i * DD * DD;
    const float* kwi  = kw   + (size_t)i * DD * DD;
    const float* vwi  = vw   + (size_t)i * DD * DD;
    const float* owi  = ow   + (size_t)i * DD * DD;
    const float* fcwi = fcw  + (size_t)i * DFFN * DD;
    const float* f2wi = fc2w + (size_t)i * DD * DFFN;
    const float* src  = (i == 0) ? x_in : xf;

    rmsnorm_kernel<<<MM, 256, 0, stream>>>(src, pn + i * DD, h);
    castw3_kernel<<<dim3(n8D / 256, 3), 256, 0, stream>>>(qwi, kwi, vwi, wbuf, n8D);
    mfma_gemm<128, 128, 0><<<dim3(QS / 128, MM / 128), 256, 0, stream>>>(
        h, wbuf, qkv, QS, DD);
    // chunked linear attention (a = h region)
    kv_trans<<<dim3(16, 32, BB), 256, 0, stream>>>(qkv, kt, vt);
    attn_phase1<<<dim3(16, HH, BB), 256, 0, stream>>>(qkv, kt, vt, h, slt);
    attn_phase2<<<dim3(8, HH, BB), 256, 0, stream>>>(slt, wcum);
    attn_phase3<<<dim3(16, HH, BB), 256, 0, stream>>>(qkv, wcum, h);
    // O-proj: xf = src + a @ ow^T   (split-K 4, atomic accumulate)
    castw_kernel<<<n8D / 256, 256, 0, stream>>>(owi, wbuf, n8D);
    init_out_kernel<<<gInit, 256, 0, stream>>>(xf, src, nullptr);
    mfma_gemm_sk<4><<<dim3(DD / 128, MM / 128, 4), 256, 0, stream>>>(h, wbuf, xf, DD, DD);
    // MLP
    rmsnorm_kernel<<<MM, 256, 0, stream>>>(xf, ln + i * DD, h);
    castw_kernel<<<n8F / 256, 256, 0, stream>>>(fcwi, wbuf, n8F);
    mfma_gemm<128, 128, 1><<<dim3(DFFN / 128, MM / 128), 256, 0, stream>>>(
        h, wbuf, f, DFFN, DD);
    castw_kernel<<<n8F / 256, 256, 0, stream>>>(f2wi, wbuf, n8F);
    float* co = (i == 1) ? (float*)d_out : xf;
    init_out_kernel<<<gInit, 256, 0, stream>>>(co, xf, fc2b + i * DD);
    mfma_gemm_sk<4><<<dim3(DD / 128, MM / 128, 4), 256, 0, stream>>>(f, wbuf, co, DD, DFFN);
  }
}